// Round 1
// baseline (227.077 us; speedup 1.0000x reference)
//
#include <hip/hip_runtime.h>
#include <hip/hip_bf16.h>

// Problem constants
#define IN_C   64
#define OUT_D  47          // (24-1)*2 - 2*1 + 3
#define XD     24
#define XSP    (XD*XD*XD)  // 13824
#define OSP    (OUT_D*OUT_D*OUT_D) // 103823
#define BATCH  16

// Effective-weight prep: Weff[c][parity(pd,ph,pw)][delta(dd,dh,dw)]
// Per dim: S(p=0,d=0)={2}, S(0,1)={0,1}, S(1,0)={1,2}, S(1,1)={0}
__global__ void weff_prep(const float* __restrict__ w, float* __restrict__ weff) {
    int c = threadIdx.x;   // 64 threads
    float wv[27];
    const float* wc = w + (size_t)c * 64 * 27;   // weight[c][0][*]
    #pragma unroll
    for (int z = 0; z < 27; z++) wv[z] = wc[z];
    const int msk[2][2] = {{4, 3}, {6, 1}};       // bit z set iff z in S(p,delta)
    #pragma unroll
    for (int pd = 0; pd < 2; pd++)
    #pragma unroll
    for (int ph = 0; ph < 2; ph++)
    #pragma unroll
    for (int pw = 0; pw < 2; pw++)
    #pragma unroll
    for (int dd = 0; dd < 2; dd++)
    #pragma unroll
    for (int dh = 0; dh < 2; dh++)
    #pragma unroll
    for (int dw = 0; dw < 2; dw++) {
        float s = 0.f;
        for (int zd = 0; zd < 3; zd++) if ((msk[pd][dd] >> zd) & 1)
            for (int zh = 0; zh < 3; zh++) if ((msk[ph][dh] >> zh) & 1)
                for (int zw = 0; zw < 3; zw++) if ((msk[pw][dw] >> zw) & 1)
                    s += wv[zd * 9 + zh * 3 + zw];
        weff[c * 64 + (((pd * 2 + ph) * 2 + pw) * 8) + ((dd * 2 + dh) * 2 + dw)] = s;
    }
}

// Main kernel: tile of m-space (MD=4, MH=8, MW=8) per block; 128 threads;
// thread (td,th,tw) handles m-voxels (2*td+{0,1}, th, tw) => 16 outputs.
#define MD 4
#define MH 8
#define MW 8
#define LZ 6
#define LY 10
#define LX 10
#define LDS_N (LZ*LY*LX)   // 600

__global__ __launch_bounds__(128) void tconv(const float* __restrict__ x,
                                             const float* __restrict__ weff,
                                             const float* __restrict__ bias,
                                             float* __restrict__ out) {
    __shared__ float xs[LDS_N];
    const int tile = blockIdx.x;       // 0..53  (6 d-tiles x 3 h x 3 w)
    const int n = blockIdx.y;
    const int tz = tile / 9;
    const int rr = tile - tz * 9;
    const int ty = rr / 3;
    const int tx = rr - ty * 3;
    const int Bd = tz * MD, Bh = ty * MH, Bw = tx * MW;

    const int tid = threadIdx.x;
    const int tw = tid & 7;
    const int th = (tid >> 3) & 7;
    const int td = tid >> 6;           // 0..1

    float acc[2][2][2][2];             // [v][pd][ph][pw]
    #pragma unroll
    for (int v = 0; v < 2; v++)
    #pragma unroll
    for (int a = 0; a < 2; a++)
    #pragma unroll
    for (int b = 0; b < 2; b++)
    #pragma unroll
    for (int d = 0; d < 2; d++) acc[v][a][b][d] = 0.f;

    const float* xn = x + (size_t)n * IN_C * XSP;

    #pragma unroll 1
    for (int c = 0; c < IN_C; c++) {
        const float* xc = xn + (size_t)c * XSP;
        // ---- stage x halo tile (zero-filled out of range) ----
        #pragma unroll
        for (int i = tid; i < LDS_N; i += 128) {
            int iz = i / (LY * LX);
            int r  = i - iz * (LY * LX);
            int iy = r / LX;
            int ix = r - iy * LX;
            int gz = Bd - 1 + iz, gy = Bh - 1 + iy, gx = Bw - 1 + ix;
            float v = 0.f;
            if ((unsigned)gz < (unsigned)XD && (unsigned)gy < (unsigned)XD &&
                (unsigned)gx < (unsigned)XD)
                v = xc[(gz * XD + gy) * XD + gx];
            xs[i] = v;
        }
        __syncthreads();

        // ---- registers: 4x3x3 neighborhood for this thread's 2 m-voxels ----
        float xv[4][3][3];
        #pragma unroll
        for (int dz = 0; dz < 4; dz++)
        #pragma unroll
        for (int dy = 0; dy < 3; dy++)
        #pragma unroll
        for (int dx = 0; dx < 3; dx++)
            xv[dz][dy][dx] = xs[(2 * td + dz) * (LY * LX) + (th + dy) * LX + (tw + dx)];

        const float* Wc = weff + c * 64;   // wave-uniform -> s_load
        #pragma unroll
        for (int pd = 0; pd < 2; pd++)
        #pragma unroll
        for (int ph = 0; ph < 2; ph++)
        #pragma unroll
        for (int pw = 0; pw < 2; pw++) {
            #pragma unroll
            for (int dd = 0; dd < 2; dd++)
            #pragma unroll
            for (int dh = 0; dh < 2; dh++)
            #pragma unroll
            for (int dw = 0; dw < 2; dw++) {
                const float wgt = Wc[(((pd * 2 + ph) * 2 + pw) * 8) +
                                     ((dd * 2 + dh) * 2 + dw)];
                acc[0][pd][ph][pw] += wgt * xv[0 + pd + dd][ph + dh][pw + dw];
                acc[1][pd][ph][pw] += wgt * xv[1 + pd + dd][ph + dh][pw + dw];
            }
        }
        __syncthreads();
    }

    // ---- epilogue: out = (acc + bias[0]) * 64 ----
    const float b0 = bias[0];
    float* on = out + (size_t)n * OSP;
    #pragma unroll
    for (int v = 0; v < 2; v++)
    #pragma unroll
    for (int pd = 0; pd < 2; pd++)
    #pragma unroll
    for (int ph = 0; ph < 2; ph++)
    #pragma unroll
    for (int pw = 0; pw < 2; pw++) {
        int od = 2 * (Bd + 2 * td + v) + pd;
        int oh = 2 * (Bh + th) + ph;
        int ow = 2 * (Bw + tw) + pw;
        if (od < OUT_D && oh < OUT_D && ow < OUT_D)
            on[(od * OUT_D + oh) * OUT_D + ow] = (acc[v][pd][ph][pw] + b0) * 64.0f;
    }
}

extern "C" void kernel_launch(void* const* d_in, const int* in_sizes, int n_in,
                              void* d_out, int out_size, void* d_ws, size_t ws_size,
                              hipStream_t stream) {
    const float* x      = (const float*)d_in[0];
    const float* weight = (const float*)d_in[1];
    const float* bias   = (const float*)d_in[2];
    float* out = (float*)d_out;
    float* weff = (float*)d_ws;        // 64*64 floats = 16 KB

    hipLaunchKernelGGL(weff_prep, dim3(1), dim3(64), 0, stream, weight, weff);

    dim3 grid(54, BATCH, 1);           // 6 x 3 x 3 tiles per batch
    hipLaunchKernelGGL(tconv, grid, dim3(128), 0, stream, x, weff, bias, out);
}

// Round 2
// 186.666 us; speedup vs baseline: 1.2165x; 1.2165x over previous
//
#include <hip/hip_runtime.h>
#include <hip/hip_bf16.h>

// Problem constants
#define IN_C   64
#define OUT_D  47          // (24-1)*2 - 2*1 + 3
#define XD     24
#define XSP    (XD*XD*XD)  // 13824
#define OSP    (OUT_D*OUT_D*OUT_D) // 103823
#define BATCH  16

#define NSPLIT 4
#define CPG    (IN_C / NSPLIT)   // 16 channels per block

// Effective-weight prep: Weff[c][parity(pd,ph,pw)][delta(dd,dh,dw)]
// Per dim: S(p=0,d=0)={2}, S(0,1)={0,1}, S(1,0)={1,2}, S(1,1)={0}
__global__ void weff_prep(const float* __restrict__ w, float* __restrict__ weff) {
    int c = threadIdx.x;   // 64 threads
    float wv[27];
    const float* wc = w + (size_t)c * 64 * 27;   // weight[c][0][*]
    #pragma unroll
    for (int z = 0; z < 27; z++) wv[z] = wc[z];
    const int msk[2][2] = {{4, 3}, {6, 1}};       // bit z set iff z in S(p,delta)
    #pragma unroll
    for (int pd = 0; pd < 2; pd++)
    #pragma unroll
    for (int ph = 0; ph < 2; ph++)
    #pragma unroll
    for (int pw = 0; pw < 2; pw++)
    #pragma unroll
    for (int dd = 0; dd < 2; dd++)
    #pragma unroll
    for (int dh = 0; dh < 2; dh++)
    #pragma unroll
    for (int dw = 0; dw < 2; dw++) {
        float s = 0.f;
        for (int zd = 0; zd < 3; zd++) if ((msk[pd][dd] >> zd) & 1)
            for (int zh = 0; zh < 3; zh++) if ((msk[ph][dh] >> zh) & 1)
                for (int zw = 0; zw < 3; zw++) if ((msk[pw][dw] >> zw) & 1)
                    s += wv[zd * 9 + zh * 3 + zw];
        weff[c * 64 + (((pd * 2 + ph) * 2 + pw) * 8) + ((dd * 2 + dh) * 2 + dw)] = s;
    }
}

// Main kernel: m-space tile 8x8x8 per block (halo 10x10x10), 256 threads,
// thread (td,th,tw) owns m-voxels (2*td+{0,1}, th, tw) -> 16 outputs.
// Each block reduces CPG=16 channels; partials combined via atomicAdd.
#define LZ 10
#define LY 10
#define LX 10
#define LDS_N (LZ*LY*LX)   // 1000

__global__ __launch_bounds__(256, 5) void tconv(const float* __restrict__ x,
                                                const float* __restrict__ weff,
                                                const float* __restrict__ bias,
                                                float* __restrict__ out) {
    __shared__ float xs[LDS_N];
    const int b = blockIdx.x;           // ((tile*4 + g)*16 + n): n fastest -> XCD spread
    const int n = b & 15;
    const int r1 = b >> 4;
    const int g = r1 & 3;
    const int t = r1 >> 2;              // 0..26 spatial tile
    const int tz = t / 9;
    const int rr = t - tz * 9;
    const int ty = rr / 3;
    const int tx = rr - ty * 3;
    const int Bd = tz * 8, Bh = ty * 8, Bw = tx * 8;

    const int tid = threadIdx.x;
    const int tw = tid & 7;
    const int th = (tid >> 3) & 7;
    const int td = tid >> 6;            // 0..3

    // ---- per-thread staging descriptors (fixed for the whole channel loop) ----
    int  sidx[4];
    int  goff[4];
    bool vld[4];
    #pragma unroll
    for (int k = 0; k < 4; k++) {
        int i = tid + 256 * k;
        sidx[k] = i;
        int iz = i / (LY * LX);
        int r2 = i - iz * (LY * LX);
        int iy = r2 / LX;
        int ix = r2 - iy * LX;
        int gz = Bd - 1 + iz, gy = Bh - 1 + iy, gx = Bw - 1 + ix;
        vld[k] = (i < LDS_N) && ((unsigned)gz < (unsigned)XD) &&
                 ((unsigned)gy < (unsigned)XD) && ((unsigned)gx < (unsigned)XD);
        goff[k] = vld[k] ? ((gz * XD + gy) * XD + gx) : 0;
    }

    const float* xg = x + (size_t)n * IN_C * XSP + (size_t)g * CPG * XSP;

    // ---- prologue: prefetch channel 0's halo into registers ----
    float pre[4];
    #pragma unroll
    for (int k = 0; k < 4; k++) pre[k] = vld[k] ? xg[goff[k]] : 0.f;

    float acc[2][2][2][2];
    #pragma unroll
    for (int v = 0; v < 2; v++)
    #pragma unroll
    for (int a = 0; a < 2; a++)
    #pragma unroll
    for (int bb = 0; bb < 2; bb++)
    #pragma unroll
    for (int d = 0; d < 2; d++) acc[v][a][bb][d] = 0.f;

    #pragma unroll 1
    for (int cc = 0; cc < CPG; cc++) {
        __syncthreads();                 // previous compute done reading xs
        #pragma unroll
        for (int k = 0; k < 4; k++)
            if (sidx[k] < LDS_N) xs[sidx[k]] = pre[k];
        __syncthreads();

        // prefetch next channel while computing this one
        if (cc + 1 < CPG) {
            const float* xc2 = xg + (size_t)(cc + 1) * XSP;
            #pragma unroll
            for (int k = 0; k < 4; k++) pre[k] = vld[k] ? xc2[goff[k]] : 0.f;
        }

        // ---- registers: 4x3x3 neighborhood for this thread's 2 m-voxels ----
        float xv[4][3][3];
        #pragma unroll
        for (int dz = 0; dz < 4; dz++)
        #pragma unroll
        for (int dy = 0; dy < 3; dy++)
        #pragma unroll
        for (int dx = 0; dx < 3; dx++)
            xv[dz][dy][dx] = xs[(2 * td + dz) * (LY * LX) + (th + dy) * LX + (tw + dx)];

        const float* Wc = weff + (g * CPG + cc) * 64;   // wave-uniform -> s_load
        #pragma unroll
        for (int pd = 0; pd < 2; pd++)
        #pragma unroll
        for (int ph = 0; ph < 2; ph++)
        #pragma unroll
        for (int pw = 0; pw < 2; pw++) {
            #pragma unroll
            for (int dd = 0; dd < 2; dd++)
            #pragma unroll
            for (int dh = 0; dh < 2; dh++)
            #pragma unroll
            for (int dw = 0; dw < 2; dw++) {
                const float wgt = Wc[(((pd * 2 + ph) * 2 + pw) * 8) +
                                     ((dd * 2 + dh) * 2 + dw)];
                acc[0][pd][ph][pw] += wgt * xv[0 + pd + dd][ph + dh][pw + dw];
                acc[1][pd][ph][pw] += wgt * xv[1 + pd + dd][ph + dh][pw + dw];
            }
        }
    }

    // ---- epilogue: atomic partial add, out += acc*64 + bias[0]*(64/NSPLIT) ----
    const float bpart = bias[0] * (64.0f / NSPLIT);
    float* on = out + (size_t)n * OSP;
    #pragma unroll
    for (int v = 0; v < 2; v++)
    #pragma unroll
    for (int pd = 0; pd < 2; pd++)
    #pragma unroll
    for (int ph = 0; ph < 2; ph++)
    #pragma unroll
    for (int pw = 0; pw < 2; pw++) {
        int od = 2 * (Bd + 2 * td + v) + pd;
        int oh = 2 * (Bh + th) + ph;
        int ow = 2 * (Bw + tw) + pw;
        if (od < OUT_D && oh < OUT_D && ow < OUT_D)
            atomicAdd(&on[(od * OUT_D + oh) * OUT_D + ow],
                      acc[v][pd][ph][pw] * 64.0f + bpart);
    }
}

extern "C" void kernel_launch(void* const* d_in, const int* in_sizes, int n_in,
                              void* d_out, int out_size, void* d_ws, size_t ws_size,
                              hipStream_t stream) {
    const float* x      = (const float*)d_in[0];
    const float* weight = (const float*)d_in[1];
    const float* bias   = (const float*)d_in[2];
    float* out = (float*)d_out;
    float* weff = (float*)d_ws;        // 64*64 floats = 16 KB

    // zero-init output (it's re-poisoned to 0xAA before every launch)
    hipMemsetAsync(out, 0, (size_t)out_size * sizeof(float), stream);

    hipLaunchKernelGGL(weff_prep, dim3(1), dim3(64), 0, stream, weight, weff);

    dim3 grid(27 * NSPLIT * BATCH, 1, 1);   // 1728 blocks, n fastest
    hipLaunchKernelGGL(tconv, grid, dim3(256), 0, stream, x, weff, bias, out);
}